// Round 2
// baseline (294.011 us; speedup 1.0000x reference)
//
#include <hip/hip_runtime.h>

#define B_ 4
#define L_ 4096
#define D_ 1152
#define T_ (B_*L_)      // 16384 tokens
#define D3_ 384
#define H_ 16
#define DK3_ 24

typedef __attribute__((ext_vector_type(4))) float f32x4;
typedef __attribute__((ext_vector_type(8))) __bf16 bf16x8;
typedef __attribute__((ext_vector_type(8))) unsigned short u16x8;

__device__ __forceinline__ unsigned short f2bf(float f) {
  unsigned int u = __float_as_uint(f);
  u += 0x7fffu + ((u >> 16) & 1u);   // round-to-nearest-even
  return (unsigned short)(u >> 16);
}
__device__ __forceinline__ float bf2f(unsigned short h) {
  return __uint_as_float(((unsigned int)h) << 16);
}

// async global->LDS, 16B per lane. LDS dest must be wave-uniform; lane l writes dest + l*16.
__device__ __forceinline__ void gl_lds16(const unsigned short* g, unsigned short* l) {
  __builtin_amdgcn_global_load_lds(
      (const __attribute__((address_space(1))) unsigned int*)g,
      (__attribute__((address_space(3))) unsigned int*)l,
      16, 0, 0);
}

// ---------------- LayerNorm: fp32 [16384,1152] -> bf16 [16384,1152] ----------------
__global__ __launch_bounds__(256) void ln_kernel(const float* __restrict__ x,
                                                 const float* __restrict__ gamma,
                                                 const float* __restrict__ beta,
                                                 unsigned short* __restrict__ xn) {
  const int row = blockIdx.x;
  const int tid = threadIdx.x;
  const float* xr = x + (size_t)row * D_;
  float v[5];
  float s = 0.f, s2 = 0.f;
#pragma unroll
  for (int j = 0; j < 5; ++j) {
    int idx = tid + j * 256;
    float val = (idx < D_) ? xr[idx] : 0.f;
    v[j] = val;
    s += val; s2 += val * val;
  }
#pragma unroll
  for (int o = 32; o > 0; o >>= 1) { s += __shfl_down(s, o); s2 += __shfl_down(s2, o); }
  __shared__ float red[8];
  int wid = tid >> 6, lane = tid & 63;
  if (lane == 0) { red[wid] = s; red[4 + wid] = s2; }
  __syncthreads();
  float ts  = red[0] + red[1] + red[2] + red[3];
  float ts2 = red[4] + red[5] + red[6] + red[7];
  const float inv = 1.f / (float)D_;
  float mean = ts * inv;
  float var  = ts2 * inv - mean * mean;
  float rstd = rsqrtf(var + 1e-6f);
  unsigned short* xo = xn + (size_t)row * D_;
#pragma unroll
  for (int j = 0; j < 5; ++j) {
    int idx = tid + j * 256;
    if (idx < D_) {
      float nv = (v[j] - mean) * rstd * gamma[idx] + beta[idx];
      xo[idx] = f2bf(nv);
    }
  }
}

// ---------------- Weight converts ----------------
__global__ void cvt_cat_wqkvg(const float* __restrict__ Wq, const float* __restrict__ Wk,
                              const float* __restrict__ Wv, const float* __restrict__ Wg,
                              unsigned short* __restrict__ out) {
  int i = blockIdx.x * 256 + threadIdx.x;
  if (i >= 4 * 147456) return;
  int p = i / 147456;
  int r = i - p * 147456;
  const float* W = (p == 0) ? Wq : (p == 1) ? Wk : (p == 2) ? Wv : Wg;
  out[i] = f2bf(W[r]);
}

__global__ void cvt_bf16(const float* __restrict__ in, unsigned short* __restrict__ out, int n) {
  int i = blockIdx.x * 256 + threadIdx.x;
  if (i < n) out[i] = f2bf(in[i]);
}

// ---------------- bf16 GEMM: C[M,N] = A[M,K] @ Bt[N,K]^T (+epilogue) ----------------
// 128x128 tile, BK=32, 4 waves (2x2), 4x4 16x16x32 fragments per wave.
// global_load_lds width=16 staging, linear LDS stride 32, m97 2-barrier loop.
// XCD-chunked block swizzle (nwg % 8 == 0 for both call sites).

template<int EPI>
__global__ __launch_bounds__(256) void gemm_bt(
    const unsigned short* __restrict__ A, const unsigned short* __restrict__ Bt,
    int K, int N,
    unsigned short* __restrict__ Cb,
    const float* __restrict__ b0, const float* __restrict__ b1,
    const float* __restrict__ b2, const float* __restrict__ b3,
    float* __restrict__ Cf, const float* __restrict__ bo,
    const float* __restrict__ xres, const float* __restrict__ gs) {
  __shared__ __align__(16) unsigned short As[128 * 32];
  __shared__ __align__(16) unsigned short Bs[128 * 32];
  const int tid = threadIdx.x;
  const int nwg = gridDim.x * gridDim.y;
  const int flat = blockIdx.y * gridDim.x + blockIdx.x;
  const int swz = (flat & 7) * (nwg >> 3) + (flat >> 3);
  const int bn = swz % gridDim.x, bm = swz / gridDim.x;

  const int wid = tid >> 6, lane = tid & 63;
  const int wr = wid >> 1, wc = wid & 1;
  const int lrow = lane & 15, kq = lane >> 4;
  const int glr = lane >> 2;         // 0..15 (row within 16-row stage chunk)
  const int glc = (lane & 3) * 8;    // 0,8,16,24 (col elems)

  const unsigned short* Ab = A + (size_t)bm * 128 * K;
  const unsigned short* Bb = Bt + (size_t)bn * 128 * K;

  f32x4 acc[4][4];
#pragma unroll
  for (int m = 0; m < 4; ++m)
#pragma unroll
    for (int n = 0; n < 4; ++n) acc[m][n] = (f32x4){0.f, 0.f, 0.f, 0.f};

  const int nk = K >> 5;
  for (int kt = 0; kt < nk; ++kt) {
    __syncthreads();   // LDS free (everyone done reading tile kt-1)
    const unsigned short* Ak = Ab + kt * 32;
    const unsigned short* Bk = Bb + kt * 32;
#pragma unroll
    for (int i = 0; i < 2; ++i) {
      const int rb = wid * 32 + i * 16;                // wave-uniform row base
      gl_lds16(Ak + (size_t)(rb + glr) * K + glc, &As[rb * 32]);
      gl_lds16(Bk + (size_t)(rb + glr) * K + glc, &Bs[rb * 32]);
    }
    __syncthreads();   // drains vmcnt -> LDS filled with tile kt

    bf16x8 af[4], bfr[4];
#pragma unroll
    for (int m = 0; m < 4; ++m)
      af[m] = *(const bf16x8*)&As[(wr * 64 + m * 16 + lrow) * 32 + kq * 8];
#pragma unroll
    for (int n = 0; n < 4; ++n)
      bfr[n] = *(const bf16x8*)&Bs[(wc * 64 + n * 16 + lrow) * 32 + kq * 8];
#pragma unroll
    for (int m = 0; m < 4; ++m)
#pragma unroll
      for (int n = 0; n < 4; ++n)
        acc[m][n] = __builtin_amdgcn_mfma_f32_16x16x32_bf16(af[m], bfr[n], acc[m][n], 0, 0, 0);
  }

  // Epilogue. D layout: col = lane&15, row = (lane>>4)*4 + reg  [m89-verified]
  const int rbase = bm * 128 + wr * 64 + kq * 4;
  const int cbase = bn * 128 + wc * 64 + lrow;
  float gv = (EPI == 1) ? gs[0] : 0.f;
#pragma unroll
  for (int m = 0; m < 4; ++m) {
#pragma unroll
    for (int n = 0; n < 4; ++n) {
      int col = cbase + n * 16;
      float bias;
      if (EPI == 0) {
        int p = (col < 384) ? 0 : (col < 768) ? 1 : (col < 1152) ? 2 : 3;
        const float* bp = (p == 0) ? b0 : (p == 1) ? b1 : (p == 2) ? b2 : b3;
        bias = bp[col - p * 384];
      } else {
        bias = bo[col];
      }
#pragma unroll
      for (int i = 0; i < 4; ++i) {
        int row = rbase + m * 16 + i;
        float val = acc[m][n][i] + bias;
        if (EPI == 0) {
          Cb[(size_t)row * N + col] = f2bf(val);
        } else {
          size_t idx = (size_t)row * N + col;
          Cf[idx] = val + xres[idx] * gv;
        }
      }
    }
  }
}

// ---------------- 3x3 attention + gate: QKVG bf16 [49152,1536] -> H bf16 [16384,1152] ----------------
__global__ __launch_bounds__(256) void attn_kernel(const unsigned short* __restrict__ QKVG,
                                                   unsigned short* __restrict__ Hout) {
  int u = blockIdx.x * 256 + threadIdx.x;   // u = t*48 + i*16 + h
  int h = u & 15;
  int ti = u >> 4;                          // = t*3 + i
  int i = ti % 3;
  int t = ti / 3;
  const unsigned short* base = QKVG + (size_t)t * 3 * 1536;
  const int co = h * 24;

  float q[24];
#pragma unroll
  for (int c = 0; c < 3; ++c) {
    u16x8 w = *(const u16x8*)(base + (size_t)i * 1536 + co + c * 8);
#pragma unroll
    for (int e = 0; e < 8; ++e) q[c * 8 + e] = bf2f(w[e]);
  }
  float s[3];
#pragma unroll
  for (int j = 0; j < 3; ++j) {
    float a = 0.f;
#pragma unroll
    for (int c = 0; c < 3; ++c) {
      u16x8 w = *(const u16x8*)(base + (size_t)j * 1536 + 384 + co + c * 8);
#pragma unroll
      for (int e = 0; e < 8; ++e) a += q[c * 8 + e] * bf2f(w[e]);
    }
    s[j] = a * 0.11785113019775793f;  // 1/sqrt(72)
  }
  float mx = fmaxf(s[0], fmaxf(s[1], s[2]));
  float e0 = __expf(s[0] - mx), e1 = __expf(s[1] - mx), e2 = __expf(s[2] - mx);
  float inv = 1.f / (e0 + e1 + e2);
  float p0 = e0 * inv, p1 = e1 * inv, p2 = e2 * inv;

  float o[24];
#pragma unroll
  for (int d = 0; d < 24; ++d) o[d] = 0.f;
  float pj[3] = {p0, p1, p2};
#pragma unroll
  for (int j = 0; j < 3; ++j) {
#pragma unroll
    for (int c = 0; c < 3; ++c) {
      u16x8 w = *(const u16x8*)(base + (size_t)j * 1536 + 768 + co + c * 8);
#pragma unroll
      for (int e = 0; e < 8; ++e) o[c * 8 + e] += pj[j] * bf2f(w[e]);
    }
  }
  unsigned short* op = Hout + (size_t)t * 1152 + (size_t)i * 384 + co;
#pragma unroll
  for (int c = 0; c < 3; ++c) {
    u16x8 w = *(const u16x8*)(base + (size_t)i * 1536 + 1152 + co + c * 8);
    u16x8 r;
#pragma unroll
    for (int e = 0; e < 8; ++e) {
      float gv = bf2f(w[e]);
      float sg = 1.f / (1.f + __expf(-gv));
      r[e] = f2bf(o[c * 8 + e] * sg);
    }
    *(u16x8*)(op + c * 8) = r;
  }
}

extern "C" void kernel_launch(void* const* d_in, const int* in_sizes, int n_in,
                              void* d_out, int out_size, void* d_ws, size_t ws_size,
                              hipStream_t stream) {
  const float* x    = (const float*)d_in[0];
  const float* ln_g = (const float*)d_in[1];
  const float* ln_b = (const float*)d_in[2];
  const float* Wq   = (const float*)d_in[3];
  const float* bq   = (const float*)d_in[4];
  const float* Wk   = (const float*)d_in[5];
  const float* bk   = (const float*)d_in[6];
  const float* Wv   = (const float*)d_in[7];
  const float* bv   = (const float*)d_in[8];
  const float* Wg   = (const float*)d_in[9];
  const float* bg   = (const float*)d_in[10];
  const float* Wo   = (const float*)d_in[11];
  const float* bo   = (const float*)d_in[12];
  const float* g    = (const float*)d_in[13];
  float* out = (float*)d_out;

  char* ws = (char*)d_ws;
  size_t off = 0;
  unsigned short* xn    = (unsigned short*)(ws + off); off += (size_t)T_ * D_ * 2;
  unsigned short* Wqkvg = (unsigned short*)(ws + off); off += (size_t)1536 * 384 * 2;
  unsigned short* Wob   = (unsigned short*)(ws + off); off += (size_t)1152 * 1152 * 2;
  unsigned short* QKVG  = (unsigned short*)(ws + off); off += (size_t)T_ * 3 * 1536 * 2;
  unsigned short* Hf    = (unsigned short*)(ws + off); off += (size_t)T_ * D_ * 2;

  ln_kernel<<<T_, 256, 0, stream>>>(x, ln_g, ln_b, xn);
  cvt_cat_wqkvg<<<(4 * 147456 + 255) / 256, 256, 0, stream>>>(Wq, Wk, Wv, Wg, Wqkvg);
  cvt_bf16<<<(1152 * 1152 + 255) / 256, 256, 0, stream>>>(Wo, Wob, 1152 * 1152);

  dim3 g1(1536 / 128, (T_ * 3) / 128);   // (12, 384) nwg=4608
  gemm_bt<0><<<g1, 256, 0, stream>>>(xn, Wqkvg, 384, 1536, QKVG, bq, bk, bv, bg,
                                     nullptr, nullptr, nullptr, nullptr);

  attn_kernel<<<(T_ * H_ * 3) / 256, 256, 0, stream>>>(QKVG, Hf);

  dim3 g2(1152 / 128, T_ / 128);         // (9, 128) nwg=1152
  gemm_bt<1><<<g2, 256, 0, stream>>>(Hf, Wob, 1152, 1152,
                                     nullptr, nullptr, nullptr, nullptr, nullptr,
                                     out, bo, x, g);
}

// Round 3
// 280.944 us; speedup vs baseline: 1.0465x; 1.0465x over previous
//
#include <hip/hip_runtime.h>

#define B_ 4
#define L_ 4096
#define D_ 1152
#define T_ (B_*L_)      // 16384 tokens
#define D3_ 384
#define H_ 16
#define DK3_ 24

typedef __attribute__((ext_vector_type(4))) float f32x4;
typedef __attribute__((ext_vector_type(8))) __bf16 bf16x8;
typedef __attribute__((ext_vector_type(8))) unsigned short u16x8;
typedef __attribute__((ext_vector_type(4))) unsigned short u16x4;

__device__ __forceinline__ unsigned short f2bf(float f) {
  unsigned int u = __float_as_uint(f);
  u += 0x7fffu + ((u >> 16) & 1u);   // round-to-nearest-even
  return (unsigned short)(u >> 16);
}
__device__ __forceinline__ float bf2f(unsigned short h) {
  return __uint_as_float(((unsigned int)h) << 16);
}

// async global->LDS, 16B per lane. LDS dest wave-uniform; lane l writes dest + l*16.
__device__ __forceinline__ void gl_lds16(const unsigned short* g, unsigned short* l) {
  __builtin_amdgcn_global_load_lds(
      (const __attribute__((address_space(1))) unsigned int*)g,
      (__attribute__((address_space(3))) unsigned int*)l,
      16, 0, 0);
}

// ---------------- LayerNorm: fp32 [16384,1152] -> bf16 [16384,1152] ----------------
// 288 float4 per row = 256 (all threads) + 32 (threads 0-31).
__global__ __launch_bounds__(256) void ln_kernel(const float* __restrict__ x,
                                                 const float* __restrict__ gamma,
                                                 const float* __restrict__ beta,
                                                 unsigned short* __restrict__ xn) {
  const int row = blockIdx.x;
  const int tid = threadIdx.x;
  const float4* xr = (const float4*)(x + (size_t)row * D_);
  float4 v0 = xr[tid];
  float4 v1 = {0.f, 0.f, 0.f, 0.f};
  const bool has2 = tid < 32;
  if (has2) v1 = xr[256 + tid];
  float s  = v0.x + v0.y + v0.z + v0.w + v1.x + v1.y + v1.z + v1.w;
  float s2 = v0.x*v0.x + v0.y*v0.y + v0.z*v0.z + v0.w*v0.w
           + v1.x*v1.x + v1.y*v1.y + v1.z*v1.z + v1.w*v1.w;
#pragma unroll
  for (int o = 32; o > 0; o >>= 1) { s += __shfl_down(s, o); s2 += __shfl_down(s2, o); }
  __shared__ float red[8];
  int wid = tid >> 6, lane = tid & 63;
  if (lane == 0) { red[wid] = s; red[4 + wid] = s2; }
  __syncthreads();
  float ts  = red[0] + red[1] + red[2] + red[3];
  float ts2 = red[4] + red[5] + red[6] + red[7];
  const float inv = 1.f / (float)D_;
  float mean = ts * inv;
  float var  = ts2 * inv - mean * mean;
  float rstd = rsqrtf(var + 1e-6f);
  const float4* gm = (const float4*)gamma;
  const float4* bt = (const float4*)beta;
  unsigned short* xo = xn + (size_t)row * D_;
  {
    float4 gv = gm[tid], bv = bt[tid];
    u16x4 r;
    r[0] = f2bf((v0.x - mean) * rstd * gv.x + bv.x);
    r[1] = f2bf((v0.y - mean) * rstd * gv.y + bv.y);
    r[2] = f2bf((v0.z - mean) * rstd * gv.z + bv.z);
    r[3] = f2bf((v0.w - mean) * rstd * gv.w + bv.w);
    *(u16x4*)(xo + tid * 4) = r;
  }
  if (has2) {
    float4 gv = gm[256 + tid], bv = bt[256 + tid];
    u16x4 r;
    r[0] = f2bf((v1.x - mean) * rstd * gv.x + bv.x);
    r[1] = f2bf((v1.y - mean) * rstd * gv.y + bv.y);
    r[2] = f2bf((v1.z - mean) * rstd * gv.z + bv.z);
    r[3] = f2bf((v1.w - mean) * rstd * gv.w + bv.w);
    *(u16x4*)(xo + (256 + tid) * 4) = r;
  }
}

// ---------------- Weight converts ----------------
__global__ void cvt_cat_wqkvg(const float* __restrict__ Wq, const float* __restrict__ Wk,
                              const float* __restrict__ Wv, const float* __restrict__ Wg,
                              unsigned short* __restrict__ out) {
  int i = blockIdx.x * 256 + threadIdx.x;
  if (i >= 4 * 147456) return;
  int p = i / 147456;
  int r = i - p * 147456;
  const float* W = (p == 0) ? Wq : (p == 1) ? Wk : (p == 2) ? Wv : Wg;
  out[i] = f2bf(W[r]);
}

__global__ void cvt_bf16(const float* __restrict__ in, unsigned short* __restrict__ out, int n) {
  int i = blockIdx.x * 256 + threadIdx.x;
  if (i < n) out[i] = f2bf(in[i]);
}

// ---------------- bf16 GEMM: C[M,N] = A[M,K] @ Bt[N,K]^T (+epilogue) ----------------
// 128x128 tile, BK=32, 4 waves (2x2), 4x4 16x16x32 frags/wave.
// Double-buffered gl_lds (issue-early), XOR(row&3) chunk swizzle both-sides,
// one __syncthreads per K-step, XCD-chunked block swizzle.

template<int EPI>
__global__ __launch_bounds__(256) void gemm_bt(
    const unsigned short* __restrict__ A, const unsigned short* __restrict__ Bt,
    int K, int N,
    unsigned short* __restrict__ Cb,
    const float* __restrict__ b0, const float* __restrict__ b1,
    const float* __restrict__ b2, const float* __restrict__ b3,
    float* __restrict__ Cf, const float* __restrict__ bo,
    const float* __restrict__ xres, const float* __restrict__ gs) {
  __shared__ __align__(16) unsigned short As[2][128 * 32];
  __shared__ __align__(16) unsigned short Bs[2][128 * 32];
  const int tid = threadIdx.x;
  const int nwg = gridDim.x * gridDim.y;
  const int flat = blockIdx.y * gridDim.x + blockIdx.x;
  const int swz = (flat & 7) * (nwg >> 3) + (flat >> 3);
  const int bn = swz % gridDim.x, bm = swz / gridDim.x;

  const int wid = tid >> 6, lane = tid & 63;
  const int wr = wid >> 1, wc = wid & 1;
  const int lrow = lane & 15, kq = lane >> 4;
  const int glr = lane >> 2;                          // 0..15 row within 16-row chunk
  const int glc = ((lane & 3) ^ (glr & 3)) * 8;       // pre-swizzled source chunk

  const unsigned short* Ab = A + (size_t)bm * 128 * K;
  const unsigned short* Bb = Bt + (size_t)bn * 128 * K;

  f32x4 acc[4][4];
#pragma unroll
  for (int m = 0; m < 4; ++m)
#pragma unroll
    for (int n = 0; n < 4; ++n) acc[m][n] = (f32x4){0.f, 0.f, 0.f, 0.f};

  // swizzled read byte-offsets (row*64 + kq*16, chunk XOR row&3; lrow&3 == row&3)
  const int kqs = (kq ^ (lrow & 3)) * 16;
  int aoff[4], boff[4];
#pragma unroll
  for (int m = 0; m < 4; ++m) aoff[m] = (wr * 64 + m * 16 + lrow) * 64 + kqs;
#pragma unroll
  for (int n = 0; n < 4; ++n) boff[n] = (wc * 64 + n * 16 + lrow) * 64 + kqs;

  const int nk = K >> 5;
#define STAGE(buf, kt)                                                        \
  {                                                                           \
    const unsigned short* Ak = Ab + (kt) * 32;                                \
    const unsigned short* Bk = Bb + (kt) * 32;                                \
    _Pragma("unroll")                                                         \
    for (int i = 0; i < 2; ++i) {                                             \
      const int rb = wid * 32 + i * 16;                                       \
      gl_lds16(Ak + (size_t)(rb + glr) * K + glc, &As[buf][rb * 32]);         \
      gl_lds16(Bk + (size_t)(rb + glr) * K + glc, &Bs[buf][rb * 32]);         \
    }                                                                         \
  }

  STAGE(0, 0);
  __syncthreads();   // drain vmcnt: tile 0 in LDS

  for (int kt = 0; kt < nk; ++kt) {
    const int cur = kt & 1;
    if (kt + 1 < nk) STAGE(cur ^ 1, kt + 1);   // issue next tile EARLY

    bf16x8 af[4], bfr[4];
#pragma unroll
    for (int m = 0; m < 4; ++m)
      af[m] = *(const bf16x8*)((const char*)As[cur] + aoff[m]);
#pragma unroll
    for (int n = 0; n < 4; ++n)
      bfr[n] = *(const bf16x8*)((const char*)Bs[cur] + boff[n]);
#pragma unroll
    for (int m = 0; m < 4; ++m)
#pragma unroll
      for (int n = 0; n < 4; ++n)
        acc[m][n] = __builtin_amdgcn_mfma_f32_16x16x32_bf16(af[m], bfr[n], acc[m][n], 0, 0, 0);

    __syncthreads();   // waves done reading cur; vmcnt(0) lands tile kt+1
  }
#undef STAGE

  // Epilogue. D layout: col = lane&15, row = (lane>>4)*4 + reg  [m89-verified]
  const int rbase = bm * 128 + wr * 64 + kq * 4;
  const int cbase = bn * 128 + wc * 64 + lrow;
  float gv = (EPI == 1) ? gs[0] : 0.f;
#pragma unroll
  for (int m = 0; m < 4; ++m) {
#pragma unroll
    for (int n = 0; n < 4; ++n) {
      int col = cbase + n * 16;
      float bias;
      if (EPI == 0) {
        int p = (col < 384) ? 0 : (col < 768) ? 1 : (col < 1152) ? 2 : 3;
        const float* bp = (p == 0) ? b0 : (p == 1) ? b1 : (p == 2) ? b2 : b3;
        bias = bp[col - p * 384];
      } else {
        bias = bo[col];
      }
#pragma unroll
      for (int i = 0; i < 4; ++i) {
        int row = rbase + m * 16 + i;
        float val = acc[m][n][i] + bias;
        if (EPI == 0) {
          Cb[(size_t)row * N + col] = f2bf(val);
        } else {
          size_t idx = (size_t)row * N + col;
          Cf[idx] = val + xres[idx] * gv;
        }
      }
    }
  }
}

// ---------------- 3x3 attention + gate: QKVG bf16 [49152,1536] -> H bf16 [16384,1152] ----------------
__global__ __launch_bounds__(256) void attn_kernel(const unsigned short* __restrict__ QKVG,
                                                   unsigned short* __restrict__ Hout) {
  int u = blockIdx.x * 256 + threadIdx.x;   // u = t*48 + i*16 + h
  int h = u & 15;
  int ti = u >> 4;                          // = t*3 + i
  int i = ti % 3;
  int t = ti / 3;
  const unsigned short* base = QKVG + (size_t)t * 3 * 1536;
  const int co = h * 24;

  float q[24];
#pragma unroll
  for (int c = 0; c < 3; ++c) {
    u16x8 w = *(const u16x8*)(base + (size_t)i * 1536 + co + c * 8);
#pragma unroll
    for (int e = 0; e < 8; ++e) q[c * 8 + e] = bf2f(w[e]);
  }
  float s[3];
#pragma unroll
  for (int j = 0; j < 3; ++j) {
    float a = 0.f;
#pragma unroll
    for (int c = 0; c < 3; ++c) {
      u16x8 w = *(const u16x8*)(base + (size_t)j * 1536 + 384 + co + c * 8);
#pragma unroll
      for (int e = 0; e < 8; ++e) a += q[c * 8 + e] * bf2f(w[e]);
    }
    s[j] = a * 0.11785113019775793f;  // 1/sqrt(72)
  }
  float mx = fmaxf(s[0], fmaxf(s[1], s[2]));
  float e0 = __expf(s[0] - mx), e1 = __expf(s[1] - mx), e2 = __expf(s[2] - mx);
  float inv = 1.f / (e0 + e1 + e2);
  float p0 = e0 * inv, p1 = e1 * inv, p2 = e2 * inv;

  float o[24];
#pragma unroll
  for (int d = 0; d < 24; ++d) o[d] = 0.f;
  float pj[3] = {p0, p1, p2};
#pragma unroll
  for (int j = 0; j < 3; ++j) {
#pragma unroll
    for (int c = 0; c < 3; ++c) {
      u16x8 w = *(const u16x8*)(base + (size_t)j * 1536 + 768 + co + c * 8);
#pragma unroll
      for (int e = 0; e < 8; ++e) o[c * 8 + e] += pj[j] * bf2f(w[e]);
    }
  }
  unsigned short* op = Hout + (size_t)t * 1152 + (size_t)i * 384 + co;
#pragma unroll
  for (int c = 0; c < 3; ++c) {
    u16x8 w = *(const u16x8*)(base + (size_t)i * 1536 + 1152 + co + c * 8);
    u16x8 r;
#pragma unroll
    for (int e = 0; e < 8; ++e) {
      float gv = bf2f(w[e]);
      float sg = 1.f / (1.f + __expf(-gv));
      r[e] = f2bf(o[c * 8 + e] * sg);
    }
    *(u16x8*)(op + c * 8) = r;
  }
}

extern "C" void kernel_launch(void* const* d_in, const int* in_sizes, int n_in,
                              void* d_out, int out_size, void* d_ws, size_t ws_size,
                              hipStream_t stream) {
  const float* x    = (const float*)d_in[0];
  const float* ln_g = (const float*)d_in[1];
  const float* ln_b = (const float*)d_in[2];
  const float* Wq   = (const float*)d_in[3];
  const float* bq   = (const float*)d_in[4];
  const float* Wk   = (const float*)d_in[5];
  const float* bk   = (const float*)d_in[6];
  const float* Wv   = (const float*)d_in[7];
  const float* bv   = (const float*)d_in[8];
  const float* Wg   = (const float*)d_in[9];
  const float* bg   = (const float*)d_in[10];
  const float* Wo   = (const float*)d_in[11];
  const float* bo   = (const float*)d_in[12];
  const float* g    = (const float*)d_in[13];
  float* out = (float*)d_out;

  char* ws = (char*)d_ws;
  size_t off = 0;
  unsigned short* xn    = (unsigned short*)(ws + off); off += (size_t)T_ * D_ * 2;
  unsigned short* Wqkvg = (unsigned short*)(ws + off); off += (size_t)1536 * 384 * 2;
  unsigned short* Wob   = (unsigned short*)(ws + off); off += (size_t)1152 * 1152 * 2;
  unsigned short* QKVG  = (unsigned short*)(ws + off); off += (size_t)T_ * 3 * 1536 * 2;
  unsigned short* Hf    = (unsigned short*)(ws + off); off += (size_t)T_ * D_ * 2;

  ln_kernel<<<T_, 256, 0, stream>>>(x, ln_g, ln_b, xn);
  cvt_cat_wqkvg<<<(4 * 147456 + 255) / 256, 256, 0, stream>>>(Wq, Wk, Wv, Wg, Wqkvg);
  cvt_bf16<<<(1152 * 1152 + 255) / 256, 256, 0, stream>>>(Wo, Wob, 1152 * 1152);

  dim3 g1(1536 / 128, (T_ * 3) / 128);   // (12, 384) nwg=4608
  gemm_bt<0><<<g1, 256, 0, stream>>>(xn, Wqkvg, 384, 1536, QKVG, bq, bk, bv, bg,
                                     nullptr, nullptr, nullptr, nullptr);

  attn_kernel<<<(T_ * H_ * 3) / 256, 256, 0, stream>>>(QKVG, Hf);

  dim3 g2(1152 / 128, T_ / 128);         // (9, 128) nwg=1152
  gemm_bt<1><<<g2, 256, 0, stream>>>(Hf, Wob, 1152, 1152,
                                     nullptr, nullptr, nullptr, nullptr, nullptr,
                                     out, bo, x, g);
}

// Round 4
// 271.474 us; speedup vs baseline: 1.0830x; 1.0349x over previous
//
#include <hip/hip_runtime.h>

#define B_ 4
#define L_ 4096
#define D_ 1152
#define T_ (B_*L_)      // 16384 tokens
#define D3_ 384
#define H_ 16
#define DK3_ 24

typedef __attribute__((ext_vector_type(4))) float f32x4;
typedef __attribute__((ext_vector_type(8))) __bf16 bf16x8;
typedef __attribute__((ext_vector_type(8))) unsigned short u16x8;
typedef __attribute__((ext_vector_type(4))) unsigned short u16x4;

__device__ __forceinline__ unsigned short f2bf(float f) {
  unsigned int u = __float_as_uint(f);
  u += 0x7fffu + ((u >> 16) & 1u);   // round-to-nearest-even
  return (unsigned short)(u >> 16);
}
__device__ __forceinline__ float bf2f(unsigned short h) {
  return __uint_as_float(((unsigned int)h) << 16);
}

// async global->LDS, 16B per lane. LDS dest wave-uniform; lane l writes dest + l*16.
__device__ __forceinline__ void gl_lds16(const unsigned short* g, unsigned short* l) {
  __builtin_amdgcn_global_load_lds(
      (const __attribute__((address_space(1))) unsigned int*)g,
      (__attribute__((address_space(3))) unsigned int*)l,
      16, 0, 0);
}

// ---------------- LayerNorm: fp32 [16384,1152] -> bf16 [16384,1152] ----------------
__global__ __launch_bounds__(256) void ln_kernel(const float* __restrict__ x,
                                                 const float* __restrict__ gamma,
                                                 const float* __restrict__ beta,
                                                 unsigned short* __restrict__ xn) {
  const int row = blockIdx.x;
  const int tid = threadIdx.x;
  const float4* xr = (const float4*)(x + (size_t)row * D_);
  float4 v0 = xr[tid];
  float4 v1 = {0.f, 0.f, 0.f, 0.f};
  const bool has2 = tid < 32;
  if (has2) v1 = xr[256 + tid];
  float s  = v0.x + v0.y + v0.z + v0.w + v1.x + v1.y + v1.z + v1.w;
  float s2 = v0.x*v0.x + v0.y*v0.y + v0.z*v0.z + v0.w*v0.w
           + v1.x*v1.x + v1.y*v1.y + v1.z*v1.z + v1.w*v1.w;
#pragma unroll
  for (int o = 32; o > 0; o >>= 1) { s += __shfl_down(s, o); s2 += __shfl_down(s2, o); }
  __shared__ float red[8];
  int wid = tid >> 6, lane = tid & 63;
  if (lane == 0) { red[wid] = s; red[4 + wid] = s2; }
  __syncthreads();
  float ts  = red[0] + red[1] + red[2] + red[3];
  float ts2 = red[4] + red[5] + red[6] + red[7];
  const float inv = 1.f / (float)D_;
  float mean = ts * inv;
  float var  = ts2 * inv - mean * mean;
  float rstd = rsqrtf(var + 1e-6f);
  const float4* gm = (const float4*)gamma;
  const float4* bt = (const float4*)beta;
  unsigned short* xo = xn + (size_t)row * D_;
  {
    float4 gv = gm[tid], bv = bt[tid];
    u16x4 r;
    r[0] = f2bf((v0.x - mean) * rstd * gv.x + bv.x);
    r[1] = f2bf((v0.y - mean) * rstd * gv.y + bv.y);
    r[2] = f2bf((v0.z - mean) * rstd * gv.z + bv.z);
    r[3] = f2bf((v0.w - mean) * rstd * gv.w + bv.w);
    *(u16x4*)(xo + tid * 4) = r;
  }
  if (has2) {
    float4 gv = gm[256 + tid], bv = bt[256 + tid];
    u16x4 r;
    r[0] = f2bf((v1.x - mean) * rstd * gv.x + bv.x);
    r[1] = f2bf((v1.y - mean) * rstd * gv.y + bv.y);
    r[2] = f2bf((v1.z - mean) * rstd * gv.z + bv.z);
    r[3] = f2bf((v1.w - mean) * rstd * gv.w + bv.w);
    *(u16x4*)(xo + (256 + tid) * 4) = r;
  }
}

// ---------------- Weight converts ----------------
__global__ void cvt_cat_wqkvg(const float* __restrict__ Wq, const float* __restrict__ Wk,
                              const float* __restrict__ Wv, const float* __restrict__ Wg,
                              unsigned short* __restrict__ out) {
  int i = blockIdx.x * 256 + threadIdx.x;
  if (i >= 4 * 147456) return;
  int p = i / 147456;
  int r = i - p * 147456;
  const float* W = (p == 0) ? Wq : (p == 1) ? Wk : (p == 2) ? Wv : Wg;
  out[i] = f2bf(W[r]);
}

__global__ void cvt_bf16(const float* __restrict__ in, unsigned short* __restrict__ out, int n) {
  int i = blockIdx.x * 256 + threadIdx.x;
  if (i < n) out[i] = f2bf(in[i]);
}

// ---------------- bf16 GEMM: C[M,N] = A[M,K] @ Bt[N,K]^T (+epilogue) ----------------
// 128x128 tile, BK=32, 4 waves (2x2), 4x4 16x16x32 frags/wave.
// 3-deep LDS ring + counted vmcnt pipeline (T4): tiles t+1,t+2 stay in flight
// across raw s_barriers; vmcnt never drained to 0 in steady state.
// Requires nk % 3 == 0 (K=384 -> 12, K=1152 -> 36).

template<int EPI>
__global__ __launch_bounds__(256) void gemm_bt(
    const unsigned short* __restrict__ A, const unsigned short* __restrict__ Bt,
    int K, int N,
    unsigned short* __restrict__ Cb,
    const float* __restrict__ b0, const float* __restrict__ b1,
    const float* __restrict__ b2, const float* __restrict__ b3,
    float* __restrict__ Cf, const float* __restrict__ bo,
    const float* __restrict__ xres, const float* __restrict__ gs) {
  __shared__ __align__(16) unsigned short As[3][128 * 32];
  __shared__ __align__(16) unsigned short Bs[3][128 * 32];
  const int tid = threadIdx.x;
  const int nwg = gridDim.x * gridDim.y;
  const int flat = blockIdx.y * gridDim.x + blockIdx.x;
  const int swz = (flat & 7) * (nwg >> 3) + (flat >> 3);
  const int bn = swz % gridDim.x, bm = swz / gridDim.x;

  const int wid = tid >> 6, lane = tid & 63;
  const int wr = wid >> 1, wc = wid & 1;
  const int lrow = lane & 15, kq = lane >> 4;
  const int glr = lane >> 2;                          // 0..15 row within 16-row chunk
  const int glc = ((lane & 3) ^ (glr & 3)) * 8;       // pre-swizzled source chunk

  const unsigned short* Ab = A + (size_t)bm * 128 * K;
  const unsigned short* Bb = Bt + (size_t)bn * 128 * K;

  f32x4 acc[4][4];
#pragma unroll
  for (int m = 0; m < 4; ++m)
#pragma unroll
    for (int n = 0; n < 4; ++n) acc[m][n] = (f32x4){0.f, 0.f, 0.f, 0.f};

  // swizzled read byte-offsets (row*64 + (kq^row&3)*16)
  const int kqs = (kq ^ (lrow & 3)) * 16;
  int aoff[4], boff[4];
#pragma unroll
  for (int m = 0; m < 4; ++m) aoff[m] = (wr * 64 + m * 16 + lrow) * 64 + kqs;
#pragma unroll
  for (int n = 0; n < 4; ++n) boff[n] = (wc * 64 + n * 16 + lrow) * 64 + kqs;

  const int nk = K >> 5;

#define STAGE(J, kt)                                                          \
  {                                                                           \
    const unsigned short* Ak = Ab + (size_t)(kt) * 32;                        \
    const unsigned short* Bk = Bb + (size_t)(kt) * 32;                        \
    _Pragma("unroll")                                                         \
    for (int i = 0; i < 2; ++i) {                                             \
      const int rb = wid * 32 + i * 16;                                       \
      gl_lds16(Ak + (size_t)(rb + glr) * K + glc, &As[J][rb * 32]);           \
      gl_lds16(Bk + (size_t)(rb + glr) * K + glc, &Bs[J][rb * 32]);           \
    }                                                                         \
  }

// One K-step on ring slot J, waiting own vmcnt down to W (literal).
#define KSTEP(J, W, kt)                                                       \
  {                                                                           \
    asm volatile("s_waitcnt vmcnt(" #W ")" ::: "memory");                     \
    __builtin_amdgcn_sched_barrier(0);                                        \
    __builtin_amdgcn_s_barrier();                                             \
    __builtin_amdgcn_sched_barrier(0);                                        \
    bf16x8 af[4], bfr[4];                                                     \
    _Pragma("unroll")                                                         \
    for (int m = 0; m < 4; ++m)                                               \
      af[m] = *(const bf16x8*)((const char*)As[J] + aoff[m]);                 \
    _Pragma("unroll")                                                         \
    for (int n = 0; n < 4; ++n)                                               \
      bfr[n] = *(const bf16x8*)((const char*)Bs[J] + boff[n]);                \
    asm volatile("s_waitcnt lgkmcnt(0)" ::: "memory");                        \
    __builtin_amdgcn_sched_barrier(0);                                        \
    __builtin_amdgcn_s_barrier();                                             \
    __builtin_amdgcn_sched_barrier(0);                                        \
    if ((kt) + 3 < nk) STAGE(J, (kt) + 3);                                    \
    __builtin_amdgcn_sched_barrier(0);                                        \
    _Pragma("unroll")                                                         \
    for (int m = 0; m < 4; ++m)                                               \
      _Pragma("unroll")                                                       \
      for (int n = 0; n < 4; ++n)                                             \
        acc[m][n] = __builtin_amdgcn_mfma_f32_16x16x32_bf16(af[m], bfr[n],    \
                                                            acc[m][n], 0,0,0);\
  }

  // prologue: stage tiles 0,1,2 (12 loads/wave in flight)
  STAGE(0, 0);
  STAGE(1, 1);
  STAGE(2, 2);

  // steady state: keep 8 loads (2 tiles) in flight past each wait
  int kt0 = 0;
  for (; kt0 < nk - 3; kt0 += 3) {
    KSTEP(0, 8, kt0);
    KSTEP(1, 8, kt0 + 1);
    KSTEP(2, 8, kt0 + 2);
  }
  // tail triple: drain 8 -> 4 -> 0
  KSTEP(0, 8, nk - 3);
  KSTEP(1, 4, nk - 2);
  KSTEP(2, 0, nk - 1);

#undef KSTEP
#undef STAGE

  // Epilogue. D layout: col = lane&15, row = (lane>>4)*4 + reg  [m89-verified]
  const int rbase = bm * 128 + wr * 64 + kq * 4;
  const int cbase = bn * 128 + wc * 64 + lrow;
  float gv = (EPI == 1) ? gs[0] : 0.f;
#pragma unroll
  for (int m = 0; m < 4; ++m) {
#pragma unroll
    for (int n = 0; n < 4; ++n) {
      int col = cbase + n * 16;
      float bias;
      if (EPI == 0) {
        int p = (col < 384) ? 0 : (col < 768) ? 1 : (col < 1152) ? 2 : 3;
        const float* bp = (p == 0) ? b0 : (p == 1) ? b1 : (p == 2) ? b2 : b3;
        bias = bp[col - p * 384];
      } else {
        bias = bo[col];
      }
#pragma unroll
      for (int i = 0; i < 4; ++i) {
        int row = rbase + m * 16 + i;
        float val = acc[m][n][i] + bias;
        if (EPI == 0) {
          Cb[(size_t)row * N + col] = f2bf(val);
        } else {
          size_t idx = (size_t)row * N + col;
          Cf[idx] = val + xres[idx] * gv;
        }
      }
    }
  }
}

// ---------------- 3x3 attention + gate: QKVG bf16 [49152,1536] -> H bf16 [16384,1152] ----------------
__global__ __launch_bounds__(256) void attn_kernel(const unsigned short* __restrict__ QKVG,
                                                   unsigned short* __restrict__ Hout) {
  int u = blockIdx.x * 256 + threadIdx.x;   // u = t*48 + i*16 + h
  int h = u & 15;
  int ti = u >> 4;                          // = t*3 + i
  int i = ti % 3;
  int t = ti / 3;
  const unsigned short* base = QKVG + (size_t)t * 3 * 1536;
  const int co = h * 24;

  float q[24];
#pragma unroll
  for (int c = 0; c < 3; ++c) {
    u16x8 w = *(const u16x8*)(base + (size_t)i * 1536 + co + c * 8);
#pragma unroll
    for (int e = 0; e < 8; ++e) q[c * 8 + e] = bf2f(w[e]);
  }
  float s[3];
#pragma unroll
  for (int j = 0; j < 3; ++j) {
    float a = 0.f;
#pragma unroll
    for (int c = 0; c < 3; ++c) {
      u16x8 w = *(const u16x8*)(base + (size_t)j * 1536 + 384 + co + c * 8);
#pragma unroll
      for (int e = 0; e < 8; ++e) a += q[c * 8 + e] * bf2f(w[e]);
    }
    s[j] = a * 0.11785113019775793f;  // 1/sqrt(72)
  }
  float mx = fmaxf(s[0], fmaxf(s[1], s[2]));
  float e0 = __expf(s[0] - mx), e1 = __expf(s[1] - mx), e2 = __expf(s[2] - mx);
  float inv = 1.f / (e0 + e1 + e2);
  float p0 = e0 * inv, p1 = e1 * inv, p2 = e2 * inv;

  float o[24];
#pragma unroll
  for (int d = 0; d < 24; ++d) o[d] = 0.f;
  float pj[3] = {p0, p1, p2};
#pragma unroll
  for (int j = 0; j < 3; ++j) {
#pragma unroll
    for (int c = 0; c < 3; ++c) {
      u16x8 w = *(const u16x8*)(base + (size_t)j * 1536 + 768 + co + c * 8);
#pragma unroll
      for (int e = 0; e < 8; ++e) o[c * 8 + e] += pj[j] * bf2f(w[e]);
    }
  }
  unsigned short* op = Hout + (size_t)t * 1152 + (size_t)i * 384 + co;
#pragma unroll
  for (int c = 0; c < 3; ++c) {
    u16x8 w = *(const u16x8*)(base + (size_t)i * 1536 + 1152 + co + c * 8);
    u16x8 r;
#pragma unroll
    for (int e = 0; e < 8; ++e) {
      float gv = bf2f(w[e]);
      float sg = 1.f / (1.f + __expf(-gv));
      r[e] = f2bf(o[c * 8 + e] * sg);
    }
    *(u16x8*)(op + c * 8) = r;
  }
}

extern "C" void kernel_launch(void* const* d_in, const int* in_sizes, int n_in,
                              void* d_out, int out_size, void* d_ws, size_t ws_size,
                              hipStream_t stream) {
  const float* x    = (const float*)d_in[0];
  const float* ln_g = (const float*)d_in[1];
  const float* ln_b = (const float*)d_in[2];
  const float* Wq   = (const float*)d_in[3];
  const float* bq   = (const float*)d_in[4];
  const float* Wk   = (const float*)d_in[5];
  const float* bk   = (const float*)d_in[6];
  const float* Wv   = (const float*)d_in[7];
  const float* bv   = (const float*)d_in[8];
  const float* Wg   = (const float*)d_in[9];
  const float* bg   = (const float*)d_in[10];
  const float* Wo   = (const float*)d_in[11];
  const float* bo   = (const float*)d_in[12];
  const float* g    = (const float*)d_in[13];
  float* out = (float*)d_out;

  char* ws = (char*)d_ws;
  size_t off = 0;
  unsigned short* xn    = (unsigned short*)(ws + off); off += (size_t)T_ * D_ * 2;
  unsigned short* Wqkvg = (unsigned short*)(ws + off); off += (size_t)1536 * 384 * 2;
  unsigned short* Wob   = (unsigned short*)(ws + off); off += (size_t)1152 * 1152 * 2;
  unsigned short* QKVG  = (unsigned short*)(ws + off); off += (size_t)T_ * 3 * 1536 * 2;
  unsigned short* Hf    = (unsigned short*)(ws + off); off += (size_t)T_ * D_ * 2;

  ln_kernel<<<T_, 256, 0, stream>>>(x, ln_g, ln_b, xn);
  cvt_cat_wqkvg<<<(4 * 147456 + 255) / 256, 256, 0, stream>>>(Wq, Wk, Wv, Wg, Wqkvg);
  cvt_bf16<<<(1152 * 1152 + 255) / 256, 256, 0, stream>>>(Wo, Wob, 1152 * 1152);

  dim3 g1(1536 / 128, (T_ * 3) / 128);   // (12, 384) nwg=4608
  gemm_bt<0><<<g1, 256, 0, stream>>>(xn, Wqkvg, 384, 1536, QKVG, bq, bk, bv, bg,
                                     nullptr, nullptr, nullptr, nullptr);

  attn_kernel<<<(T_ * H_ * 3) / 256, 256, 0, stream>>>(QKVG, Hf);

  dim3 g2(1152 / 128, T_ / 128);         // (9, 128) nwg=1152
  gemm_bt<1><<<g2, 256, 0, stream>>>(Hf, Wob, 1152, 1152,
                                     nullptr, nullptr, nullptr, nullptr, nullptr,
                                     out, bo, x, g);
}

// Round 5
// 264.432 us; speedup vs baseline: 1.1119x; 1.0266x over previous
//
#include <hip/hip_runtime.h>

#define B_ 4
#define L_ 4096
#define D_ 1152
#define T_ (B_*L_)      // 16384 tokens
#define D3_ 384
#define H_ 16
#define DK3_ 24

typedef __attribute__((ext_vector_type(4))) float f32x4;
typedef __attribute__((ext_vector_type(8))) __bf16 bf16x8;
typedef __attribute__((ext_vector_type(8))) unsigned short u16x8;
typedef __attribute__((ext_vector_type(4))) unsigned short u16x4;

__device__ __forceinline__ unsigned short f2bf(float f) {
  unsigned int u = __float_as_uint(f);
  u += 0x7fffu + ((u >> 16) & 1u);   // round-to-nearest-even
  return (unsigned short)(u >> 16);
}
__device__ __forceinline__ float bf2f(unsigned short h) {
  return __uint_as_float(((unsigned int)h) << 16);
}

// async global->LDS, 16B per lane. LDS dest wave-uniform; lane l writes dest + l*16.
__device__ __forceinline__ void gl_lds16(const unsigned short* g, unsigned short* l) {
  __builtin_amdgcn_global_load_lds(
      (const __attribute__((address_space(1))) unsigned int*)g,
      (__attribute__((address_space(3))) unsigned int*)l,
      16, 0, 0);
}

// ---------------- LayerNorm: fp32 [16384,1152] -> bf16 [16384,1152] ----------------
__global__ __launch_bounds__(256) void ln_kernel(const float* __restrict__ x,
                                                 const float* __restrict__ gamma,
                                                 const float* __restrict__ beta,
                                                 unsigned short* __restrict__ xn) {
  const int row = blockIdx.x;
  const int tid = threadIdx.x;
  const float4* xr = (const float4*)(x + (size_t)row * D_);
  float4 v0 = xr[tid];
  float4 v1 = {0.f, 0.f, 0.f, 0.f};
  const bool has2 = tid < 32;
  if (has2) v1 = xr[256 + tid];
  float s  = v0.x + v0.y + v0.z + v0.w + v1.x + v1.y + v1.z + v1.w;
  float s2 = v0.x*v0.x + v0.y*v0.y + v0.z*v0.z + v0.w*v0.w
           + v1.x*v1.x + v1.y*v1.y + v1.z*v1.z + v1.w*v1.w;
#pragma unroll
  for (int o = 32; o > 0; o >>= 1) { s += __shfl_down(s, o); s2 += __shfl_down(s2, o); }
  __shared__ float red[8];
  int wid = tid >> 6, lane = tid & 63;
  if (lane == 0) { red[wid] = s; red[4 + wid] = s2; }
  __syncthreads();
  float ts  = red[0] + red[1] + red[2] + red[3];
  float ts2 = red[4] + red[5] + red[6] + red[7];
  const float inv = 1.f / (float)D_;
  float mean = ts * inv;
  float var  = ts2 * inv - mean * mean;
  float rstd = rsqrtf(var + 1e-6f);
  const float4* gm = (const float4*)gamma;
  const float4* bt = (const float4*)beta;
  unsigned short* xo = xn + (size_t)row * D_;
  {
    float4 gv = gm[tid], bv = bt[tid];
    u16x4 r;
    r[0] = f2bf((v0.x - mean) * rstd * gv.x + bv.x);
    r[1] = f2bf((v0.y - mean) * rstd * gv.y + bv.y);
    r[2] = f2bf((v0.z - mean) * rstd * gv.z + bv.z);
    r[3] = f2bf((v0.w - mean) * rstd * gv.w + bv.w);
    *(u16x4*)(xo + tid * 4) = r;
  }
  if (has2) {
    float4 gv = gm[256 + tid], bv = bt[256 + tid];
    u16x4 r;
    r[0] = f2bf((v1.x - mean) * rstd * gv.x + bv.x);
    r[1] = f2bf((v1.y - mean) * rstd * gv.y + bv.y);
    r[2] = f2bf((v1.z - mean) * rstd * gv.z + bv.z);
    r[3] = f2bf((v1.w - mean) * rstd * gv.w + bv.w);
    *(u16x4*)(xo + (256 + tid) * 4) = r;
  }
}

// ---------------- Weight converts ----------------
__global__ void cvt_cat_wqkvg(const float* __restrict__ Wq, const float* __restrict__ Wk,
                              const float* __restrict__ Wv, const float* __restrict__ Wg,
                              unsigned short* __restrict__ out) {
  int i = blockIdx.x * 256 + threadIdx.x;
  if (i >= 4 * 147456) return;
  int p = i / 147456;
  int r = i - p * 147456;
  const float* W = (p == 0) ? Wq : (p == 1) ? Wk : (p == 2) ? Wv : Wg;
  out[i] = f2bf(W[r]);
}

__global__ void cvt_bf16(const float* __restrict__ in, unsigned short* __restrict__ out, int n) {
  int i = blockIdx.x * 256 + threadIdx.x;
  if (i < n) out[i] = f2bf(in[i]);
}

// ---------------- 256x128 deep-pipelined bf16 GEMM ----------------
// BM=256, BN=128, BK=64. 8 waves (4M x 2N), wave-tile 64x64, 4x4 16x16x32 frags.
// LDS: 3-slot ring, slot = A[2 slab][256][32] (32KB) + B[2 slab][128][32] (16KB) = 48KB.
// st_16x32 swizzle: row with (r&8): column elems ^16 (byte ^32), applied on the
// global SOURCE for gl_lds (linear dest) and on ds_read addresses (involution).
// Counted vmcnt(6) steady state; ONE barrier per K-tile; stage tile kt+2 during kt.

__device__ __forceinline__ void stage_unit(const unsigned short* Ab, const unsigned short* Bb,
                                           int K, int kt, unsigned short* slotbase,
                                           int u, int lane) {
  const int r_in = lane >> 2;
  const int scol = ((lane & 3) * 8) ^ ((lane & 32) ? 16 : 0);
  const unsigned short* src;
  if (u < 32) {   // A units: rows (u>>1)*16 .. +15, slab u&1
    const int r0 = (u >> 1) * 16, slab = u & 1;
    src = Ab + (size_t)(r0 + r_in) * K + kt * 64 + slab * 32 + scol;
  } else {        // B units
    const int ub = u - 32;
    const int r0 = (ub >> 1) * 16, slab = ub & 1;
    src = Bb + (size_t)(r0 + r_in) * K + kt * 64 + slab * 32 + scol;
  }
  gl_lds16(src, slotbase + u * 512);
}

template<int EPI>
__global__ __launch_bounds__(512) void gemm256(
    const unsigned short* __restrict__ A, const unsigned short* __restrict__ Bt,
    int K, int N,
    unsigned short* __restrict__ Cb,
    const float* __restrict__ b0, const float* __restrict__ b1,
    const float* __restrict__ b2, const float* __restrict__ b3,
    float* __restrict__ Cf, const float* __restrict__ bo,
    const float* __restrict__ xres, const float* __restrict__ gs) {
  extern __shared__ unsigned short lds[];   // 3 * 24576 ushorts = 144 KB
  char* ldsc = (char*)lds;

  const int tid = threadIdx.x;
  const int nwg = gridDim.x * gridDim.y;
  const int flat = blockIdx.y * gridDim.x + blockIdx.x;
  const int swz = (flat & 7) * (nwg >> 3) + (flat >> 3);
  const int bn = swz % gridDim.x, bm = swz / gridDim.x;

  const int wid = tid >> 6, lane = tid & 63;
  const int wm = wid >> 1, wn = wid & 1;
  const int lrow16 = lane & 15, kq = lane >> 4;
  // swizzled per-lane ds_read byte offset within a unit-group
  const int vbyte = lrow16 * 64 + ((kq * 16) ^ ((lrow16 & 8) ? 32 : 0));

  const unsigned short* Ab = A + (size_t)bm * 256 * K;
  const unsigned short* Bb = Bt + (size_t)bn * 128 * K;

  f32x4 acc[4][4];
#pragma unroll
  for (int m = 0; m < 4; ++m)
#pragma unroll
    for (int n = 0; n < 4; ++n) acc[m][n] = (f32x4){0.f, 0.f, 0.f, 0.f};

  const int nk = K >> 6;   // K-tiles of 64

#define STAGE3(J2, kt2, j0)                                                   \
  _Pragma("unroll")                                                           \
  for (int jj = (j0); jj < (j0) + 3; ++jj)                                    \
    stage_unit(Ab, Bb, K, (kt2), lds + (J2) * 24576, wid * 6 + jj, lane);

#define STAGE6(J2, kt2)                                                       \
  _Pragma("unroll")                                                           \
  for (int jj = 0; jj < 6; ++jj)                                              \
    stage_unit(Ab, Bb, K, (kt2), lds + (J2) * 24576, wid * 6 + jj, lane);

#define KT_STEP(J, W, kt, STG)                                                \
  {                                                                           \
    asm volatile("s_waitcnt vmcnt(" #W ")" ::: "memory");                     \
    __builtin_amdgcn_sched_barrier(0);                                        \
    __builtin_amdgcn_s_barrier();                                             \
    __builtin_amdgcn_sched_barrier(0);                                        \
    const char* sA = ldsc + (J) * 49152;                                      \
    const char* sB = ldsc + (J) * 49152 + 32768;                              \
    bf16x8 bf[4][2], af0[2][2], af1[2][2];                                    \
    _Pragma("unroll")                                                         \
    for (int n = 0; n < 4; ++n)                                               \
      _Pragma("unroll")                                                       \
      for (int s = 0; s < 2; ++s)                                             \
        bf[n][s] = *(const bf16x8*)(sB + wn * 8192 + (n * 2 + s) * 1024 + vbyte); \
    _Pragma("unroll")                                                         \
    for (int m = 0; m < 2; ++m)                                               \
      _Pragma("unroll")                                                       \
      for (int s = 0; s < 2; ++s)                                             \
        af0[m][s] = *(const bf16x8*)(sA + wm * 8192 + (m * 2 + s) * 1024 + vbyte); \
    if (STG) { STAGE3(((J) + 2) % 3, (kt) + 2, 0); }                          \
    __builtin_amdgcn_s_setprio(1);                                            \
    _Pragma("unroll")                                                         \
    for (int s = 0; s < 2; ++s)                                               \
      _Pragma("unroll")                                                       \
      for (int m = 0; m < 2; ++m)                                             \
        _Pragma("unroll")                                                     \
        for (int n = 0; n < 4; ++n)                                           \
          acc[m][n] = __builtin_amdgcn_mfma_f32_16x16x32_bf16(af0[m][s], bf[n][s], acc[m][n], 0, 0, 0); \
    __builtin_amdgcn_s_setprio(0);                                            \
    _Pragma("unroll")                                                         \
    for (int m = 0; m < 2; ++m)                                               \
      _Pragma("unroll")                                                       \
      for (int s = 0; s < 2; ++s)                                             \
        af1[m][s] = *(const bf16x8*)(sA + wm * 8192 + ((m + 2) * 2 + s) * 1024 + vbyte); \
    if (STG) { STAGE3(((J) + 2) % 3, (kt) + 2, 3); }                          \
    __builtin_amdgcn_s_setprio(1);                                            \
    _Pragma("unroll")                                                         \
    for (int s = 0; s < 2; ++s)                                               \
      _Pragma("unroll")                                                       \
      for (int m = 0; m < 2; ++m)                                             \
        _Pragma("unroll")                                                     \
        for (int n = 0; n < 4; ++n)                                           \
          acc[m + 2][n] = __builtin_amdgcn_mfma_f32_16x16x32_bf16(af1[m][s], bf[n][s], acc[m + 2][n], 0, 0, 0); \
    __builtin_amdgcn_s_setprio(0);                                            \
  }

  // prologue: stage tiles 0 and 1 (12 gl_lds per wave in flight)
  STAGE6(0, 0);
  STAGE6(1, 1);

  for (int kt0 = 0; kt0 < nk - 3; kt0 += 3) {
    KT_STEP(0, 6, kt0, 1);
    KT_STEP(1, 6, kt0 + 1, 1);
    KT_STEP(2, 6, kt0 + 2, 1);
  }
  KT_STEP(0, 6, nk - 3, 1);   // stages tile nk-1
  KT_STEP(1, 6, nk - 2, 0);
  KT_STEP(2, 0, nk - 1, 0);

#undef KT_STEP
#undef STAGE6
#undef STAGE3

  // Epilogue. D layout: col = lane&15 (N-side), row = (lane>>4)*4 + reg (M-side)
  const int rbase = bm * 256 + wm * 64 + kq * 4;
  const int cbase = bn * 128 + wn * 64 + lrow16;
  float gv = (EPI == 1) ? gs[0] : 0.f;
#pragma unroll
  for (int m = 0; m < 4; ++m) {
#pragma unroll
    for (int n = 0; n < 4; ++n) {
      int col = cbase + n * 16;
      float bias;
      if (EPI == 0) {
        int p = (col < 384) ? 0 : (col < 768) ? 1 : (col < 1152) ? 2 : 3;
        const float* bp = (p == 0) ? b0 : (p == 1) ? b1 : (p == 2) ? b2 : b3;
        bias = bp[col - p * 384];
      } else {
        bias = bo[col];
      }
#pragma unroll
      for (int i = 0; i < 4; ++i) {
        int row = rbase + m * 16 + i;
        float val = acc[m][n][i] + bias;
        if (EPI == 0) {
          Cb[(size_t)row * N + col] = f2bf(val);
        } else {
          size_t idx = (size_t)row * N + col;
          Cf[idx] = val + xres[idx] * gv;
        }
      }
    }
  }
}

// ---------------- 3x3 attention + gate: QKVG bf16 [49152,1536] -> H bf16 [16384,1152] ----------------
__global__ __launch_bounds__(256) void attn_kernel(const unsigned short* __restrict__ QKVG,
                                                   unsigned short* __restrict__ Hout) {
  int u = blockIdx.x * 256 + threadIdx.x;   // u = t*48 + i*16 + h
  int h = u & 15;
  int ti = u >> 4;                          // = t*3 + i
  int i = ti % 3;
  int t = ti / 3;
  const unsigned short* base = QKVG + (size_t)t * 3 * 1536;
  const int co = h * 24;

  float q[24];
#pragma unroll
  for (int c = 0; c < 3; ++c) {
    u16x8 w = *(const u16x8*)(base + (size_t)i * 1536 + co + c * 8);
#pragma unroll
    for (int e = 0; e < 8; ++e) q[c * 8 + e] = bf2f(w[e]);
  }
  float s[3];
#pragma unroll
  for (int j = 0; j < 3; ++j) {
    float a = 0.f;
#pragma unroll
    for (int c = 0; c < 3; ++c) {
      u16x8 w = *(const u16x8*)(base + (size_t)j * 1536 + 384 + co + c * 8);
#pragma unroll
      for (int e = 0; e < 8; ++e) a += q[c * 8 + e] * bf2f(w[e]);
    }
    s[j] = a * 0.11785113019775793f;  // 1/sqrt(72)
  }
  float mx = fmaxf(s[0], fmaxf(s[1], s[2]));
  float e0 = __expf(s[0] - mx), e1 = __expf(s[1] - mx), e2 = __expf(s[2] - mx);
  float inv = 1.f / (e0 + e1 + e2);
  float p0 = e0 * inv, p1 = e1 * inv, p2 = e2 * inv;

  float o[24];
#pragma unroll
  for (int d = 0; d < 24; ++d) o[d] = 0.f;
  float pj[3] = {p0, p1, p2};
#pragma unroll
  for (int j = 0; j < 3; ++j) {
#pragma unroll
    for (int c = 0; c < 3; ++c) {
      u16x8 w = *(const u16x8*)(base + (size_t)j * 1536 + 768 + co + c * 8);
#pragma unroll
      for (int e = 0; e < 8; ++e) o[c * 8 + e] += pj[j] * bf2f(w[e]);
    }
  }
  unsigned short* op = Hout + (size_t)t * 1152 + (size_t)i * 384 + co;
#pragma unroll
  for (int c = 0; c < 3; ++c) {
    u16x8 w = *(const u16x8*)(base + (size_t)i * 1536 + 1152 + co + c * 8);
    u16x8 r;
#pragma unroll
    for (int e = 0; e < 8; ++e) {
      float gv = bf2f(w[e]);
      float sg = 1.f / (1.f + __expf(-gv));
      r[e] = f2bf(o[c * 8 + e] * sg);
    }
    *(u16x8*)(op + c * 8) = r;
  }
}

extern "C" void kernel_launch(void* const* d_in, const int* in_sizes, int n_in,
                              void* d_out, int out_size, void* d_ws, size_t ws_size,
                              hipStream_t stream) {
  const float* x    = (const float*)d_in[0];
  const float* ln_g = (const float*)d_in[1];
  const float* ln_b = (const float*)d_in[2];
  const float* Wq   = (const float*)d_in[3];
  const float* bq   = (const float*)d_in[4];
  const float* Wk   = (const float*)d_in[5];
  const float* bk   = (const float*)d_in[6];
  const float* Wv   = (const float*)d_in[7];
  const float* bv   = (const float*)d_in[8];
  const float* Wg   = (const float*)d_in[9];
  const float* bg   = (const float*)d_in[10];
  const float* Wo   = (const float*)d_in[11];
  const float* bo   = (const float*)d_in[12];
  const float* g    = (const float*)d_in[13];
  float* out = (float*)d_out;

  char* ws = (char*)d_ws;
  size_t off = 0;
  unsigned short* xn    = (unsigned short*)(ws + off); off += (size_t)T_ * D_ * 2;
  unsigned short* Wqkvg = (unsigned short*)(ws + off); off += (size_t)1536 * 384 * 2;
  unsigned short* Wob   = (unsigned short*)(ws + off); off += (size_t)1152 * 1152 * 2;
  unsigned short* QKVG  = (unsigned short*)(ws + off); off += (size_t)T_ * 3 * 1536 * 2;
  unsigned short* Hf    = (unsigned short*)(ws + off); off += (size_t)T_ * D_ * 2;

  const int LDS_BYTES = 3 * 49152;  // 144 KB
  (void)hipFuncSetAttribute(reinterpret_cast<const void*>(&gemm256<0>),
                            hipFuncAttributeMaxDynamicSharedMemorySize, LDS_BYTES);
  (void)hipFuncSetAttribute(reinterpret_cast<const void*>(&gemm256<1>),
                            hipFuncAttributeMaxDynamicSharedMemorySize, LDS_BYTES);

  ln_kernel<<<T_, 256, 0, stream>>>(x, ln_g, ln_b, xn);
  cvt_cat_wqkvg<<<(4 * 147456 + 255) / 256, 256, 0, stream>>>(Wq, Wk, Wv, Wg, Wqkvg);
  cvt_bf16<<<(1152 * 1152 + 255) / 256, 256, 0, stream>>>(Wo, Wob, 1152 * 1152);

  dim3 g1(1536 / 128, (T_ * 3) / 256);   // (12, 192) nwg=2304, %8==0
  gemm256<0><<<g1, 512, LDS_BYTES, stream>>>(xn, Wqkvg, 384, 1536, QKVG, bq, bk, bv, bg,
                                             nullptr, nullptr, nullptr, nullptr);

  attn_kernel<<<(T_ * H_ * 3) / 256, 256, 0, stream>>>(QKVG, Hf);

  dim3 g2(1152 / 128, T_ / 256);         // (9, 64) nwg=576, %8==0
  gemm256<1><<<g2, 512, LDS_BYTES, stream>>>(Hf, Wob, 1152, 1152,
                                             nullptr, nullptr, nullptr, nullptr, nullptr,
                                             out, bo, x, g);
}